// Round 8
// baseline (308.846 us; speedup 1.0000x reference)
//
#include <hip/hip_runtime.h>

#define B_ 16
#define C_ 192
#define T_ 2048
#define F_ 256
#define HALF_ 96

typedef short s16x8 __attribute__((ext_vector_type(8)));
typedef float f32x4 __attribute__((ext_vector_type(4)));
typedef unsigned short ushort;

union U8 { uint4 v; ushort u[8]; };
union U4 { uint2 v; ushort u[4]; };

__device__ __forceinline__ ushort f2bf(float f) {
  unsigned u = __float_as_uint(f);
  unsigned r = u + 0x7fff + ((u >> 16) & 1);
  return (ushort)(r >> 16);
}
__device__ __forceinline__ float bf2f(ushort h) {
  return __uint_as_float(((unsigned)h) << 16);
}
// packed f32x2 -> bf16x2 (RNE), single HW inst; lo <- %1, hi <- %2
__device__ __forceinline__ unsigned cvt_pk_bf16(float lo, float hi) {
  unsigned r;
  asm("v_cvt_pk_bf16_f32 %0, %1, %2" : "=v"(r) : "v"(lo), "v"(hi));
  return r;
}
// tanh-form gelu on raw v_exp_f32
__device__ __forceinline__ float gelu_f(float x) {
  float x3 = x * x * x;
  float z = fmaf(0.0356774081f, x3, 0.7978845608f * x);
  float az = fabsf(z);
  float e = __builtin_amdgcn_exp2f(az * -2.885390082f);  // exp(-2az)
  float th = (1.f - e) * __builtin_amdgcn_rcpf(1.f + e);
  th = copysignf(th, z);
  return 0.5f * x * (1.f + th);
}

// ---------------------------------------------------------------------------
// Weight converters -> MFMA-fragment order: wq[tile][ks][lane][8], so a wave's
// A-load is base + lane*16B (fully coalesced). lane = quad*16+col encodes
// row = tile*16+col, k = ks*32+quad*8+e.
// ---------------------------------------------------------------------------
__global__ void wcvt_prj_k(const float* __restrict__ w, const float* __restrict__ pb,
                           ushort* __restrict__ wq, float* __restrict__ pbp) {
  int d = blockIdx.x * 256 + threadIdx.x;   // 12*16*8*64*8 = 786432
  if (d >= 786432) return;
  int e = d & 7;
  int lane = (d >> 3) & 63;
  int ks = (d >> 9) & 7;
  int mtile = (d >> 12) & 15;
  int chunk = d >> 16;
  int col = lane & 15, quad = lane >> 4;
  int pr_loc = mtile * 16 + col;            // permuted local row = j*8+ch_i
  int k = ks * 32 + quad * 8 + e;
  float val = 0.f;
  if (pr_loc < 232) {
    int j = pr_loc >> 3, ch_i = pr_loc & 7;
    int r = chunk * 232 + ch_i * 29 + j;    // original row
    val = w[(size_t)r * 256 + k];
    if (ks == 0 && quad == 0 && e == 0) pbp[chunk * 232 + pr_loc] = pb[r];
  }
  wq[d] = f2bf(val);
}

__global__ void wcvt_pw_k(const float* __restrict__ pw_w, ushort* __restrict__ wq) {
  int d = blockIdx.x * 256 + threadIdx.x;   // 3*16*8*64*8 = 196608
  if (d >= 196608) return;
  int e = d & 7;
  int lane = (d >> 3) & 63;
  int ks = (d >> 9) & 7;
  int mtile = (d >> 12) & 15;
  int l = d >> 16;
  int col = lane & 15, quad = lane >> 4;
  int row = mtile * 16 + col, k = ks * 32 + quad * 8 + e;
  wq[d] = f2bf(pw_w[(size_t)(l * 256 + row) * 256 + k]);
}

__global__ void wcvt_pre_k(const float* __restrict__ pre_w, ushort* __restrict__ wq) {
  int d = blockIdx.x * 256 + threadIdx.x;   // 16*3*64*8 = 24576
  if (d >= 24576) return;
  int e = d & 7;
  int idx = d >> 3;
  int lane = idx & 63; idx >>= 6;
  int ks = idx % 3, mtile = idx / 3;
  int col = lane & 15, quad = lane >> 4;
  int row = mtile * 16 + col, k = ks * 32 + quad * 8 + e;
  wq[d] = f2bf(pre_w[row * 96 + k]);
}

// ---------------------------------------------------------------------------
// K1: pre GEMM via MFMA, 32-t tiles. x0 fp32 [c][t] -> hT bf16 [b][t][c]
// ---------------------------------------------------------------------------
__global__ __launch_bounds__(256, 4) void pre_k(
    const float* __restrict__ x, const ushort* __restrict__ wb,
    const float* __restrict__ pb, ushort* __restrict__ hT) {
  __shared__ ushort xb[32 * 104];
  __shared__ __align__(16) ushort ob[32 * 264];
  int tid = threadIdx.x;
  int b = blockIdx.y;
  int t0 = blockIdx.x * 32;
#pragma unroll
  for (int p = 0; p < 12; ++p) {
    int idx = tid + p * 256;
    int c = idx >> 5, t = idx & 31;
    xb[t * 104 + c] = f2bf(x[((size_t)b * C_ + c) * T_ + t0 + t]);
  }
  __syncthreads();
  int lane = tid & 63, wid = tid >> 6, col = lane & 15, quad = lane >> 4;
  f32x4 acc[4][2];
#pragma unroll
  for (int mt = 0; mt < 4; ++mt)
#pragma unroll
    for (int nt = 0; nt < 2; ++nt) acc[mt][nt] = (f32x4)(0.f);
#pragma unroll
  for (int ks = 0; ks < 3; ++ks) {
    int kloc = ks * 32 + quad * 8;
    s16x8 av[4];
#pragma unroll
    for (int mt = 0; mt < 4; ++mt)
      av[mt] = *(const s16x8*)(wb + ((((wid * 4 + mt) * 3 + ks) * 64 + lane) << 3));
#pragma unroll
    for (int nt = 0; nt < 2; ++nt) {
      s16x8 bv = *(const s16x8*)(xb + (nt * 16 + col) * 104 + kloc);
#pragma unroll
      for (int mt = 0; mt < 4; ++mt)
        acc[mt][nt] = __builtin_amdgcn_mfma_f32_16x16x32_bf16(av[mt], bv, acc[mt][nt], 0, 0, 0);
    }
  }
  float pbv[4][4];
#pragma unroll
  for (int mt = 0; mt < 4; ++mt)
    *(float4*)pbv[mt] = *(const float4*)(pb + (wid * 4 + mt) * 16 + quad * 4);
#pragma unroll
  for (int nt = 0; nt < 2; ++nt) {
    int t = nt * 16 + col;
#pragma unroll
    for (int mt = 0; mt < 4; ++mt) {
      int o = (wid * 4 + mt) * 16 + quad * 4;
      uint2 wv2;
      wv2.x = cvt_pk_bf16(acc[mt][nt][0] + pbv[mt][0], acc[mt][nt][1] + pbv[mt][1]);
      wv2.y = cvt_pk_bf16(acc[mt][nt][2] + pbv[mt][2], acc[mt][nt][3] + pbv[mt][3]);
      *(uint2*)&ob[t * 264 + o] = wv2;
    }
  }
  __syncthreads();
#pragma unroll
  for (int p = 0; p < 4; ++p) {
    int idx = tid + p * 256;
    int trow = idx >> 5, cc = (idx & 31) * 8;
    *(uint4*)(hT + ((size_t)b * T_ + t0 + trow) * F_ + cc) =
        *(const uint4*)&ob[trow * 264 + cc];
  }
}

// ---------------------------------------------------------------------------
// K2: fused layer, 32-t tiles. GEMM A-loads 2-deep pipelined (even/odd ks).
// ---------------------------------------------------------------------------
template <bool MASK_OUT>
__global__ __launch_bounds__(256, 4) void layer_k(
    const ushort* __restrict__ hT_in, ushort* __restrict__ hT_out,
    const float* __restrict__ mask,
    const float* __restrict__ dww, const float* __restrict__ dwb,
    const float* __restrict__ g1, const float* __restrict__ b1,
    const ushort* __restrict__ pw, const float* __restrict__ pwb,
    const float* __restrict__ g2, const float* __restrict__ b2,
    int dil) {
  __shared__ __align__(16) ushort y1b[32 * 264];
  __shared__ float stat[64];
  float* scratch = (float*)y1b;
  int tid = threadIdx.x;
  int b = blockIdx.y;
  int t0 = blockIdx.x * 32;
  const ushort* hb = hT_in + (size_t)b * T_ * F_;
  const float* mrow = mask + (size_t)b * T_;

  // ---- Phase A: conv + norm1 + gelu ----
  {
    int lane32 = tid & 31;
    int half = tid >> 5;
    int c0 = lane32 * 8;
    float dwl[24], dbv[8], g1v[8], b1v[8];
#pragma unroll
    for (int q = 0; q < 6; ++q)
      *(float4*)&dwl[q * 4] = *(const float4*)(dww + c0 * 3 + q * 4);
    *(float4*)&dbv[0] = *(const float4*)(dwb + c0);
    *(float4*)&dbv[4] = *(const float4*)(dwb + c0 + 4);
    *(float4*)&g1v[0] = *(const float4*)(g1 + c0);
    *(float4*)&g1v[4] = *(const float4*)(g1 + c0 + 4);
    *(float4*)&b1v[0] = *(const float4*)(b1 + c0);
    *(float4*)&b1v[4] = *(const float4*)(b1 + c0 + 4);
    uint4 zero4 = make_uint4(0, 0, 0, 0);
#pragma unroll 1
    for (int pass = 0; pass < 4; ++pass) {
      int t = pass * 8 + half;
      int tz = t0 + t, tm = tz - dil, tp = tz + dil;
      bool vm = (tm >= 0), vp = (tp < T_);
      float mm = vm ? mrow[tm] : 0.f;
      float mz = mrow[tz];
      float mp = vp ? mrow[tp] : 0.f;
      U8 r0, r1, r2;
      r0.v = vm ? *(const uint4*)(hb + (size_t)tm * F_ + c0) : zero4;
      r1.v = *(const uint4*)(hb + (size_t)tz * F_ + c0);
      r2.v = vp ? *(const uint4*)(hb + (size_t)tp * F_ + c0) : zero4;
      float v[8];
      float s = 0.f, q = 0.f;
#pragma unroll
      for (int i = 0; i < 8; ++i) {
        float vv = fmaf(dwl[i * 3], bf2f(r0.u[i]) * mm,
                   fmaf(dwl[i * 3 + 1], bf2f(r1.u[i]) * mz,
                   fmaf(dwl[i * 3 + 2], bf2f(r2.u[i]) * mp, dbv[i])));
        v[i] = vv;
        s += vv;
        q = fmaf(vv, vv, q);
      }
#pragma unroll
      for (int m = 1; m < 32; m <<= 1) {
        s += __shfl_xor(s, m, 32);
        q += __shfl_xor(q, m, 32);
      }
      float mean = s * (1.f / 256.f);
      float var = q * (1.f / 256.f) - mean * mean;
      float rstd = rsqrtf(var + 1e-5f);
      float gv[8];
#pragma unroll
      for (int i = 0; i < 8; ++i)
        gv[i] = gelu_f((v[i] - mean) * rstd * g1v[i] + b1v[i]);
      uint4 pk4;
      pk4.x = cvt_pk_bf16(gv[0], gv[1]);
      pk4.y = cvt_pk_bf16(gv[2], gv[3]);
      pk4.z = cvt_pk_bf16(gv[4], gv[5]);
      pk4.w = cvt_pk_bf16(gv[6], gv[7]);
      *(uint4*)&y1b[t * 264 + c0] = pk4;
    }
  }
  __syncthreads();
  // ---- Phase B: MFMA GEMM, A-loads 2-deep pipelined ----
  int lane = tid & 63, wid = tid >> 6, col = lane & 15, quad = lane >> 4;
  f32x4 acc[4][2];
#pragma unroll
  for (int mt = 0; mt < 4; ++mt)
#pragma unroll
    for (int nt = 0; nt < 2; ++nt) acc[mt][nt] = (f32x4)(0.f);
  {
    s16x8 avc[4], avn[4];
#pragma unroll
    for (int mt = 0; mt < 4; ++mt)
      avc[mt] = *(const s16x8*)(pw + ((((wid * 4 + mt) * 8 + 0) * 64 + lane) << 3));
#pragma unroll 1
    for (int ks2 = 0; ks2 < 4; ++ks2) {
      int ke = ks2 * 2, ko = ke + 1;
#pragma unroll
      for (int mt = 0; mt < 4; ++mt)
        avn[mt] = *(const s16x8*)(pw + ((((wid * 4 + mt) * 8 + ko) * 64 + lane) << 3));
      {
        int kloc = ke * 32 + quad * 8;
#pragma unroll
        for (int nt = 0; nt < 2; ++nt) {
          s16x8 bv = *(const s16x8*)(y1b + (nt * 16 + col) * 264 + kloc);
#pragma unroll
          for (int mt = 0; mt < 4; ++mt)
            acc[mt][nt] = __builtin_amdgcn_mfma_f32_16x16x32_bf16(avc[mt], bv, acc[mt][nt], 0, 0, 0);
        }
      }
      if (ks2 < 3) {
#pragma unroll
        for (int mt = 0; mt < 4; ++mt)
          avc[mt] = *(const s16x8*)(pw + ((((wid * 4 + mt) * 8 + ko + 1) * 64 + lane) << 3));
      }
      {
        int kloc = ko * 32 + quad * 8;
#pragma unroll
        for (int nt = 0; nt < 2; ++nt) {
          s16x8 bv = *(const s16x8*)(y1b + (nt * 16 + col) * 264 + kloc);
#pragma unroll
          for (int mt = 0; mt < 4; ++mt)
            acc[mt][nt] = __builtin_amdgcn_mfma_f32_16x16x32_bf16(avn[mt], bv, acc[mt][nt], 0, 0, 0);
        }
      }
    }
  }
  __syncthreads();
  // ---- Phase C: bias + per-t stats ----
  float pwbv[4][4];
#pragma unroll
  for (int mt = 0; mt < 4; ++mt)
    *(float4*)pwbv[mt] = *(const float4*)(pwb + (wid * 4 + mt) * 16 + quad * 4);
#pragma unroll
  for (int nt = 0; nt < 2; ++nt) {
    float s = 0.f, q = 0.f;
#pragma unroll
    for (int mt = 0; mt < 4; ++mt)
#pragma unroll
      for (int r = 0; r < 4; ++r) {
        float v = acc[mt][nt][r] + pwbv[mt][r];
        acc[mt][nt][r] = v;
        s += v;
        q = fmaf(v, v, q);
      }
    int pcol = (wid * 4 + quad) * 32 + nt * 16 + col;
    scratch[pcol] = s;
    scratch[512 + pcol] = q;
  }
  __syncthreads();
  if (tid < 32) {
    float s = 0.f, q = 0.f;
#pragma unroll
    for (int p = 0; p < 16; ++p) {
      s += scratch[p * 32 + tid];
      q += scratch[512 + p * 32 + tid];
    }
    float mean = s * (1.f / 256.f);
    float var = q * (1.f / 256.f) - mean * mean;
    stat[tid] = mean;
    stat[32 + tid] = rsqrtf(var + 1e-5f);
  }
  __syncthreads();
  // ---- Phase D: norm2 + gelu -> y1b ----
  {
    float g2v[4][4], b2v[4][4];
#pragma unroll
    for (int mt = 0; mt < 4; ++mt) {
      *(float4*)g2v[mt] = *(const float4*)(g2 + (wid * 4 + mt) * 16 + quad * 4);
      *(float4*)b2v[mt] = *(const float4*)(b2 + (wid * 4 + mt) * 16 + quad * 4);
    }
#pragma unroll
    for (int nt = 0; nt < 2; ++nt) {
      int t = nt * 16 + col;
      float mean = stat[t], rstd = stat[32 + t];
#pragma unroll
      for (int mt = 0; mt < 4; ++mt) {
        int o = (wid * 4 + mt) * 16 + quad * 4;
        float u0 = gelu_f((acc[mt][nt][0] - mean) * rstd * g2v[mt][0] + b2v[mt][0]);
        float u1 = gelu_f((acc[mt][nt][1] - mean) * rstd * g2v[mt][1] + b2v[mt][1]);
        float u2 = gelu_f((acc[mt][nt][2] - mean) * rstd * g2v[mt][2] + b2v[mt][2]);
        float u3 = gelu_f((acc[mt][nt][3] - mean) * rstd * g2v[mt][3] + b2v[mt][3]);
        uint2 wv2;
        wv2.x = cvt_pk_bf16(u0, u1);
        wv2.y = cvt_pk_bf16(u2, u3);
        *(uint2*)&y1b[t * 264 + o] = wv2;
      }
    }
  }
  __syncthreads();
  // ---- Phase E: coalesced residual + store ----
#pragma unroll
  for (int p = 0; p < 4; ++p) {
    int idx = tid + p * 256;
    int trow = idx >> 5, cc = (idx & 31) * 8;
    int t = t0 + trow;
    U8 yv, rv;
    yv.v = *(const uint4*)&y1b[trow * 264 + cc];
    rv.v = *(const uint4*)(hb + (size_t)t * F_ + cc);
    float mval = MASK_OUT ? mrow[t] : 1.f;
    float hv[8];
#pragma unroll
    for (int i = 0; i < 8; ++i) {
      float h = bf2f(rv.u[i]) + bf2f(yv.u[i]);
      hv[i] = MASK_OUT ? h * mval : h;
    }
    uint4 wv4;
    wv4.x = cvt_pk_bf16(hv[0], hv[1]);
    wv4.y = cvt_pk_bf16(hv[2], hv[3]);
    wv4.z = cvt_pk_bf16(hv[4], hv[5]);
    wv4.w = cvt_pk_bf16(hv[6], hv[7]);
    *(uint4*)(hT_out + ((size_t)b * T_ + t) * F_ + cc) = wv4;
  }
}

// ---------------------------------------------------------------------------
// K3: proj GEMM + RQ spline + logdet + x0-copy.
// B staged in MFMA-fragment order: 16B block f = (nt*8+ks)*64 + quad*16 + col
// holds hT[(t0+nt*16+col)*F + (ks*4+quad)*8 ..+7]. LDS writes AND GEMM B-reads
// are then base + lane*16B -> bank-conflict-free (old 264-stride layout was an
// 8-way conflict on ds_read_b128: 512 extra cycles/block = the whole 3.15M).
// Staging region 16384 u; s-tile [ch][t][j] (2440/38) aliases it post-barrier.
// A-loads 2-deep pipelined (R7). launch_bounds(256,4) — (256,5) spills (R3).
// ---------------------------------------------------------------------------
__global__ __launch_bounds__(256, 4) void proj_spline_k(
    const ushort* __restrict__ hT,
    const float* __restrict__ x, const float* __restrict__ mask,
    const ushort* __restrict__ w_bf, const float* __restrict__ pbp,
    float* __restrict__ out, float* __restrict__ logdet) {
  __shared__ __align__(16) ushort bsm[19520];   // max(16384 staging, 19520 s-tile)
  __shared__ float red[4];
  ushort* s_lds = bsm;

  int tid = threadIdx.x;
  int t0 = blockIdx.x * 64;
  int chunk = blockIdx.y;
  int b = blockIdx.z;
  int lane = tid & 63, wid = tid >> 6, col = lane & 15, quad = lane >> 4;

  // ---- staging: fragment-order, lane-contiguous LDS writes ----
#pragma unroll
  for (int p = 0; p < 8; ++p) {
    int f = tid + p * 256;                  // 16B-block id in fragment order
    int fnt = f >> 9, fks = (f >> 6) & 7, fq = (f >> 4) & 3, fc = f & 15;
    int t = fnt * 16 + fc;
    int u = fks * 4 + fq;
    *(uint4*)(bsm + f * 8) =
        *(const uint4*)(hT + ((size_t)b * T_ + t0 + t) * F_ + u * 8);
  }
  // folded x0-copy
#pragma unroll
  for (int p = 0; p < 2; ++p) {
    int idx = tid + p * 256;
    int ch = idx >> 6, t = idx & 63;
    out[((size_t)b * C_ + chunk * 8 + ch) * T_ + t0 + t] =
        x[((size_t)b * C_ + chunk * 8 + ch) * T_ + t0 + t] * mask[(size_t)b * T_ + t0 + t];
  }
  f32x4 acc[4][4];
#pragma unroll
  for (int mt = 0; mt < 4; ++mt)
#pragma unroll
    for (int nt = 0; nt < 4; ++nt) acc[mt][nt] = (f32x4)(0.f);
  const ushort* wchunk = w_bf + (size_t)chunk * 65536;
  __syncthreads();
  {
    s16x8 avc[4], avn[4];
#pragma unroll
    for (int mt = 0; mt < 4; ++mt)
      avc[mt] = *(const s16x8*)(wchunk + ((((wid * 4 + mt) * 8 + 0) * 64 + lane) << 3));
#pragma unroll 1
    for (int ks2 = 0; ks2 < 4; ++ks2) {
      int ke = ks2 * 2, ko = ke + 1;
#pragma unroll
      for (int mt = 0; mt < 4; ++mt)
        avn[mt] = *(const s16x8*)(wchunk + ((((wid * 4 + mt) * 8 + ko) * 64 + lane) << 3));
#pragma unroll
      for (int nt = 0; nt < 4; ++nt) {
        s16x8 bv = *(const s16x8*)(bsm + (((nt * 8 + ke) * 64 + lane) << 3));
#pragma unroll
        for (int mt = 0; mt < 4; ++mt)
          acc[mt][nt] = __builtin_amdgcn_mfma_f32_16x16x32_bf16(avc[mt], bv, acc[mt][nt], 0, 0, 0);
      }
      if (ks2 < 3) {
#pragma unroll
        for (int mt = 0; mt < 4; ++mt)
          avc[mt] = *(const s16x8*)(wchunk + ((((wid * 4 + mt) * 8 + ko + 1) * 64 + lane) << 3));
      }
#pragma unroll
      for (int nt = 0; nt < 4; ++nt) {
        s16x8 bv = *(const s16x8*)(bsm + (((nt * 8 + ko) * 64 + lane) << 3));
#pragma unroll
        for (int mt = 0; mt < 4; ++mt)
          acc[mt][nt] = __builtin_amdgcn_mfma_f32_16x16x32_bf16(avn[mt], bv, acc[mt][nt], 0, 0, 0);
      }
    }
  }
  __syncthreads();
  // ---- write s-tile (permuted rows) -> [ch][t][j], strides 2440/38 ----
  {
    float mv[4];
#pragma unroll
    for (int nt = 0; nt < 4; ++nt)
      mv[nt] = mask[(size_t)b * T_ + t0 + nt * 16 + col];
#pragma unroll
    for (int mt = 0; mt < 4; ++mt) {
#pragma unroll
      for (int r = 0; r < 4; ++r) {
        int local = (wid * 4 + mt) * 16 + quad * 4 + r;
        if (local < 232) {
          int ch_i = local & 7, j = local >> 3;
          float bias = pbp[chunk * 232 + local];
          ushort* bp = s_lds + ch_i * 2440 + j;
          unsigned p01 = cvt_pk_bf16((acc[mt][0][r] + bias) * mv[0],
                                     (acc[mt][1][r] + bias) * mv[1]);
          unsigned p23 = cvt_pk_bf16((acc[mt][2][r] + bias) * mv[2],
                                     (acc[mt][3][r] + bias) * mv[3]);
          bp[col * 38]        = (ushort)p01;
          bp[(16 + col) * 38] = (ushort)(p01 >> 16);
          bp[(32 + col) * 38] = (ushort)p23;
          bp[(48 + col) * 38] = (ushort)(p23 >> 16);
        }
      }
    }
  }
  __syncthreads();
  // ---- spline ----
  float lad_sum = 0.f;
  int ch_i = tid >> 5, ti = tid & 31;
  int ch = chunk * 8 + ch_i;
#pragma unroll 1
  for (int pass = 0; pass < 2; ++pass) {
    int t = ti + pass * 32;
    const ushort* sp = s_lds + ch_i * 2440 + t * 38;
    float s[29];
#pragma unroll
    for (int jj = 0; jj < 14; ++jj) {
      unsigned w = *(const unsigned*)(sp + jj * 2);
      s[jj * 2]     = __uint_as_float(w << 16);
      s[jj * 2 + 1] = __uint_as_float(w & 0xffff0000u);
    }
    s[28] = bf2f(sp[28]);
    float xin = x[((size_t)b * C_ + HALF_ + ch) * T_ + t0 + t];
    float mval = mask[(size_t)b * T_ + t0 + t];
    const float KE = 0.09016844f;   // 0.0625 * log2(e)
    float ew[10], eh[10];
    float esw = 0.f, esh = 0.f;
#pragma unroll
    for (int j = 0; j < 10; ++j) { ew[j] = __builtin_amdgcn_exp2f(s[j] * KE); esw += ew[j]; }
#pragma unroll
    for (int j = 0; j < 10; ++j) { eh[j] = __builtin_amdgcn_exp2f(s[10 + j] * KE); esh += eh[j]; }
    // cw_{k+1} = cw_k + 0.01 + 9.9*ew[k]/esw   (== 10*(0.001+0.99*softmax) - 5 chain)
    float aw = 9.9f * __builtin_amdgcn_rcpf(esw);
    float ah = 9.9f * __builtin_amdgcn_rcpf(esh);
    float xc = fminf(fmaxf(xin, -5.f), 5.f);
    bool inside = (xin >= -5.f) && (xin <= 5.f);
    // k = 1
    float cw1 = fmaf(aw, ew[0], -4.99f);
    float ch1 = fmaf(ah, eh[0], -4.99f);
    bool sel1 = (xc >= cw1);
    float in_cw = sel1 ? cw1 : -5.f;
    float in_ch = sel1 ? ch1 : -5.f;
    float hi_cw = cw1, hi_ch = ch1;
    float u0 = s[20];       // dv knot pre-softplus for idx (valid when idx>=1)
    float u1 = s[20];       // dv knot pre-softplus for idx+1 (valid when idx<=8)
    float cwp = cw1 + 0.01f, chp = ch1 + 0.01f;
    bool psel = sel1;
    // k = 2..9: running select of {lower knot (sel_k), upper knot (sel_{k-1})}
#pragma unroll
    for (int k = 2; k <= 9; ++k) {
      float cwk = fmaf(aw, ew[k - 1], cwp);
      float chk = fmaf(ah, eh[k - 1], chp);
      bool sel = (xc >= cwk);
      hi_cw = psel ? cwk : hi_cw;
      hi_ch = psel ? chk : hi_ch;
      u1    = psel ? s[19 + k] : u1;
      in_cw = sel ? cwk : in_cw;
      in_ch = sel ? chk : in_ch;
      u0    = sel ? s[19 + k] : u0;
      psel = sel;
      cwp = cwk + 0.01f;
      chp = chk + 0.01f;
    }
    // k = 10 edge: cw[10] = chh[10] = 5, dv[10] = 1; idx==0 edge: dv[0] = 1
    hi_cw = psel ? 5.f : hi_cw;
    hi_ch = psel ? 5.f : hi_ch;
    float e0 = __expf(u0);
    float sp0 = (u0 > 15.f) ? u0 : __logf(1.f + e0);
    float d0 = sel1 ? (0.001f + sp0) : 1.f;
    float e1 = __expf(u1);
    float sp1 = (u1 > 15.f) ? u1 : __logf(1.f + e1);
    float d1 = psel ? 1.f : (0.001f + sp1);
    float in_w = hi_cw - in_cw;
    float in_h = hi_ch - in_ch;
    float rw = __builtin_amdgcn_rcpf(in_w);
    float theta = (xc - in_cw) * rw;
    float delta = in_h * rw;
    float omt = 1.f - theta;
    float t1m = theta * omt;
    float th2 = theta * theta;
    float denom = delta + (d0 + d1 - 2.f * delta) * t1m;
    float rd = __builtin_amdgcn_rcpf(denom);
    float num = in_h * (delta * th2 + d0 * t1m);
    float outv = in_ch + num * rd;
    float dnum = delta * delta * (d1 * th2 + 2.f * delta * t1m + d0 * omt * omt);
    float lad = __logf(dnum * rd * rd);
    float res = inside ? outv : xin;
    float ladv = inside ? lad : 0.f;
    out[((size_t)b * C_ + HALF_ + ch) * T_ + t0 + t] = res * mval;
    lad_sum += ladv * mval;
  }
#pragma unroll
  for (int off = 32; off > 0; off >>= 1)
    lad_sum += __shfl_down(lad_sum, off, 64);
  if ((tid & 63) == 0) red[tid >> 6] = lad_sum;
  __syncthreads();
  if (tid == 0)
    atomicAdd(logdet + b, red[0] + red[1] + red[2] + red[3]);
}

extern "C" void kernel_launch(void* const* d_in, const int* in_sizes, int n_in,
                              void* d_out, int out_size, void* d_ws, size_t ws_size,
                              hipStream_t stream) {
  const float* x      = (const float*)d_in[0];
  const float* mask   = (const float*)d_in[1];
  const float* pre_w  = (const float*)d_in[2];
  const float* pre_b  = (const float*)d_in[3];
  const float* dw_w   = (const float*)d_in[4];
  const float* dw_b   = (const float*)d_in[5];
  const float* pw_w   = (const float*)d_in[6];
  const float* pw_b   = (const float*)d_in[7];
  const float* g1     = (const float*)d_in[8];
  const float* b1     = (const float*)d_in[9];
  const float* g2     = (const float*)d_in[10];
  const float* b2     = (const float*)d_in[11];
  const float* proj_w = (const float*)d_in[12];
  const float* proj_b = (const float*)d_in[13];
  float* out = (float*)d_out;
  float* logdet = out + (size_t)B_ * C_ * T_;

  const size_t HSZ = (size_t)B_ * T_ * F_;
  ushort* hA    = (ushort*)d_ws;
  ushort* hB    = hA + HSZ;
  ushort* wprj  = hB + HSZ;                  // 786432 (fragment order, padded)
  ushort* wpw   = wprj + 786432;             // 196608
  ushort* wpre  = wpw + 196608;              // 24576
  float*  pbp   = (float*)(wpre + 24576);    // 2784 floats

  hipMemsetAsync(logdet, 0, B_ * sizeof(float), stream);
  wcvt_prj_k<<<dim3(786432 / 256), 256, 0, stream>>>(proj_w, proj_b, wprj, pbp);
  wcvt_pw_k<<<dim3(196608 / 256), 256, 0, stream>>>(pw_w, wpw);
  wcvt_pre_k<<<dim3(24576 / 256), 256, 0, stream>>>(pre_w, wpre);

  pre_k<<<dim3(T_ / 32, B_), 256, 0, stream>>>(x, wpre, pre_b, hA);

  layer_k<false><<<dim3(T_ / 32, B_), 256, 0, stream>>>(hA, hB, mask,
      dw_w, dw_b, g1, b1, wpw, pw_b, g2, b2, 1);
  layer_k<false><<<dim3(T_ / 32, B_), 256, 0, stream>>>(hB, hA, mask,
      dw_w + F_ * 3, dw_b + F_, g1 + F_, b1 + F_,
      wpw + 65536, pw_b + F_, g2 + F_, b2 + F_, 3);
  layer_k<true><<<dim3(T_ / 32, B_), 256, 0, stream>>>(hA, hB, mask,
      dw_w + 2 * F_ * 3, dw_b + 2 * F_, g1 + 2 * F_, b1 + 2 * F_,
      wpw + 2 * 65536, pw_b + 2 * F_, g2 + 2 * F_, b2 + 2 * F_, 9);

  proj_spline_k<<<dim3(T_ / 64, 12, B_), 256, 0, stream>>>(hB, x, mask,
      wprj, pbp, out, logdet);
}

// Round 9
// 301.318 us; speedup vs baseline: 1.0250x; 1.0250x over previous
//
#include <hip/hip_runtime.h>

#define B_ 16
#define C_ 192
#define T_ 2048
#define F_ 256
#define HALF_ 96

typedef short s16x8 __attribute__((ext_vector_type(8)));
typedef float f32x4 __attribute__((ext_vector_type(4)));
typedef unsigned short ushort;

union U8 { uint4 v; ushort u[8]; };
union U4 { uint2 v; ushort u[4]; };

__device__ __forceinline__ ushort f2bf(float f) {
  unsigned u = __float_as_uint(f);
  unsigned r = u + 0x7fff + ((u >> 16) & 1);
  return (ushort)(r >> 16);
}
__device__ __forceinline__ float bf2f(ushort h) {
  return __uint_as_float(((unsigned)h) << 16);
}
// packed f32x2 -> bf16x2 (RNE), single HW inst; lo <- %1, hi <- %2
__device__ __forceinline__ unsigned cvt_pk_bf16(float lo, float hi) {
  unsigned r;
  asm("v_cvt_pk_bf16_f32 %0, %1, %2" : "=v"(r) : "v"(lo), "v"(hi));
  return r;
}
// tanh-form gelu on raw v_exp_f32
__device__ __forceinline__ float gelu_f(float x) {
  float x3 = x * x * x;
  float z = fmaf(0.0356774081f, x3, 0.7978845608f * x);
  float az = fabsf(z);
  float e = __builtin_amdgcn_exp2f(az * -2.885390082f);  // exp(-2az)
  float th = (1.f - e) * __builtin_amdgcn_rcpf(1.f + e);
  th = copysignf(th, z);
  return 0.5f * x * (1.f + th);
}

// ---------------------------------------------------------------------------
// Weight converters -> MFMA-fragment order: wq[tile][ks][lane][8], so a wave's
// A-load is base + lane*16B (fully coalesced). lane = quad*16+col encodes
// row = tile*16+col, k = ks*32+quad*8+e.
// ---------------------------------------------------------------------------
__global__ void wcvt_prj_k(const float* __restrict__ w, const float* __restrict__ pb,
                           ushort* __restrict__ wq, float* __restrict__ pbp) {
  int d = blockIdx.x * 256 + threadIdx.x;   // 12*16*8*64*8 = 786432
  if (d >= 786432) return;
  int e = d & 7;
  int lane = (d >> 3) & 63;
  int ks = (d >> 9) & 7;
  int mtile = (d >> 12) & 15;
  int chunk = d >> 16;
  int col = lane & 15, quad = lane >> 4;
  int pr_loc = mtile * 16 + col;            // permuted local row = j*8+ch_i
  int k = ks * 32 + quad * 8 + e;
  float val = 0.f;
  if (pr_loc < 232) {
    int j = pr_loc >> 3, ch_i = pr_loc & 7;
    int r = chunk * 232 + ch_i * 29 + j;    // original row
    val = w[(size_t)r * 256 + k];
    if (ks == 0 && quad == 0 && e == 0) pbp[chunk * 232 + pr_loc] = pb[r];
  }
  wq[d] = f2bf(val);
}

__global__ void wcvt_pw_k(const float* __restrict__ pw_w, ushort* __restrict__ wq) {
  int d = blockIdx.x * 256 + threadIdx.x;   // 3*16*8*64*8 = 196608
  if (d >= 196608) return;
  int e = d & 7;
  int lane = (d >> 3) & 63;
  int ks = (d >> 9) & 7;
  int mtile = (d >> 12) & 15;
  int l = d >> 16;
  int col = lane & 15, quad = lane >> 4;
  int row = mtile * 16 + col, k = ks * 32 + quad * 8 + e;
  wq[d] = f2bf(pw_w[(size_t)(l * 256 + row) * 256 + k]);
}

__global__ void wcvt_pre_k(const float* __restrict__ pre_w, ushort* __restrict__ wq) {
  int d = blockIdx.x * 256 + threadIdx.x;   // 16*3*64*8 = 24576
  if (d >= 24576) return;
  int e = d & 7;
  int idx = d >> 3;
  int lane = idx & 63; idx >>= 6;
  int ks = idx % 3, mtile = idx / 3;
  int col = lane & 15, quad = lane >> 4;
  int row = mtile * 16 + col, k = ks * 32 + quad * 8 + e;
  wq[d] = f2bf(pre_w[row * 96 + k]);
}

// ---------------------------------------------------------------------------
// K1: pre GEMM via MFMA, 32-t tiles. x0 fp32 [c][t] -> hT bf16 [b][t][c]
// ---------------------------------------------------------------------------
__global__ __launch_bounds__(256, 4) void pre_k(
    const float* __restrict__ x, const ushort* __restrict__ wb,
    const float* __restrict__ pb, ushort* __restrict__ hT) {
  __shared__ ushort xb[32 * 104];
  __shared__ __align__(16) ushort ob[32 * 264];
  int tid = threadIdx.x;
  int b = blockIdx.y;
  int t0 = blockIdx.x * 32;
#pragma unroll
  for (int p = 0; p < 12; ++p) {
    int idx = tid + p * 256;
    int c = idx >> 5, t = idx & 31;
    xb[t * 104 + c] = f2bf(x[((size_t)b * C_ + c) * T_ + t0 + t]);
  }
  __syncthreads();
  int lane = tid & 63, wid = tid >> 6, col = lane & 15, quad = lane >> 4;
  f32x4 acc[4][2];
#pragma unroll
  for (int mt = 0; mt < 4; ++mt)
#pragma unroll
    for (int nt = 0; nt < 2; ++nt) acc[mt][nt] = (f32x4)(0.f);
#pragma unroll
  for (int ks = 0; ks < 3; ++ks) {
    int kloc = ks * 32 + quad * 8;
    s16x8 av[4];
#pragma unroll
    for (int mt = 0; mt < 4; ++mt)
      av[mt] = *(const s16x8*)(wb + ((((wid * 4 + mt) * 3 + ks) * 64 + lane) << 3));
#pragma unroll
    for (int nt = 0; nt < 2; ++nt) {
      s16x8 bv = *(const s16x8*)(xb + (nt * 16 + col) * 104 + kloc);
#pragma unroll
      for (int mt = 0; mt < 4; ++mt)
        acc[mt][nt] = __builtin_amdgcn_mfma_f32_16x16x32_bf16(av[mt], bv, acc[mt][nt], 0, 0, 0);
    }
  }
  float pbv[4][4];
#pragma unroll
  for (int mt = 0; mt < 4; ++mt)
    *(float4*)pbv[mt] = *(const float4*)(pb + (wid * 4 + mt) * 16 + quad * 4);
#pragma unroll
  for (int nt = 0; nt < 2; ++nt) {
    int t = nt * 16 + col;
#pragma unroll
    for (int mt = 0; mt < 4; ++mt) {
      int o = (wid * 4 + mt) * 16 + quad * 4;
      uint2 wv2;
      wv2.x = cvt_pk_bf16(acc[mt][nt][0] + pbv[mt][0], acc[mt][nt][1] + pbv[mt][1]);
      wv2.y = cvt_pk_bf16(acc[mt][nt][2] + pbv[mt][2], acc[mt][nt][3] + pbv[mt][3]);
      *(uint2*)&ob[t * 264 + o] = wv2;
    }
  }
  __syncthreads();
#pragma unroll
  for (int p = 0; p < 4; ++p) {
    int idx = tid + p * 256;
    int trow = idx >> 5, cc = (idx & 31) * 8;
    *(uint4*)(hT + ((size_t)b * T_ + t0 + trow) * F_ + cc) =
        *(const uint4*)&ob[trow * 264 + cc];
  }
}

// ---------------------------------------------------------------------------
// K2: fused layer, 32-t tiles. GEMM A-loads 2-deep pipelined (even/odd ks).
// ---------------------------------------------------------------------------
template <bool MASK_OUT>
__global__ __launch_bounds__(256, 4) void layer_k(
    const ushort* __restrict__ hT_in, ushort* __restrict__ hT_out,
    const float* __restrict__ mask,
    const float* __restrict__ dww, const float* __restrict__ dwb,
    const float* __restrict__ g1, const float* __restrict__ b1,
    const ushort* __restrict__ pw, const float* __restrict__ pwb,
    const float* __restrict__ g2, const float* __restrict__ b2,
    int dil) {
  __shared__ __align__(16) ushort y1b[32 * 264];
  __shared__ float stat[64];
  float* scratch = (float*)y1b;
  int tid = threadIdx.x;
  int b = blockIdx.y;
  int t0 = blockIdx.x * 32;
  const ushort* hb = hT_in + (size_t)b * T_ * F_;
  const float* mrow = mask + (size_t)b * T_;

  // ---- Phase A: conv + norm1 + gelu ----
  {
    int lane32 = tid & 31;
    int half = tid >> 5;
    int c0 = lane32 * 8;
    float dwl[24], dbv[8], g1v[8], b1v[8];
#pragma unroll
    for (int q = 0; q < 6; ++q)
      *(float4*)&dwl[q * 4] = *(const float4*)(dww + c0 * 3 + q * 4);
    *(float4*)&dbv[0] = *(const float4*)(dwb + c0);
    *(float4*)&dbv[4] = *(const float4*)(dwb + c0 + 4);
    *(float4*)&g1v[0] = *(const float4*)(g1 + c0);
    *(float4*)&g1v[4] = *(const float4*)(g1 + c0 + 4);
    *(float4*)&b1v[0] = *(const float4*)(b1 + c0);
    *(float4*)&b1v[4] = *(const float4*)(b1 + c0 + 4);
    uint4 zero4 = make_uint4(0, 0, 0, 0);
#pragma unroll 1
    for (int pass = 0; pass < 4; ++pass) {
      int t = pass * 8 + half;
      int tz = t0 + t, tm = tz - dil, tp = tz + dil;
      bool vm = (tm >= 0), vp = (tp < T_);
      float mm = vm ? mrow[tm] : 0.f;
      float mz = mrow[tz];
      float mp = vp ? mrow[tp] : 0.f;
      U8 r0, r1, r2;
      r0.v = vm ? *(const uint4*)(hb + (size_t)tm * F_ + c0) : zero4;
      r1.v = *(const uint4*)(hb + (size_t)tz * F_ + c0);
      r2.v = vp ? *(const uint4*)(hb + (size_t)tp * F_ + c0) : zero4;
      float v[8];
      float s = 0.f, q = 0.f;
#pragma unroll
      for (int i = 0; i < 8; ++i) {
        float vv = fmaf(dwl[i * 3], bf2f(r0.u[i]) * mm,
                   fmaf(dwl[i * 3 + 1], bf2f(r1.u[i]) * mz,
                   fmaf(dwl[i * 3 + 2], bf2f(r2.u[i]) * mp, dbv[i])));
        v[i] = vv;
        s += vv;
        q = fmaf(vv, vv, q);
      }
#pragma unroll
      for (int m = 1; m < 32; m <<= 1) {
        s += __shfl_xor(s, m, 32);
        q += __shfl_xor(q, m, 32);
      }
      float mean = s * (1.f / 256.f);
      float var = q * (1.f / 256.f) - mean * mean;
      float rstd = rsqrtf(var + 1e-5f);
      float gv[8];
#pragma unroll
      for (int i = 0; i < 8; ++i)
        gv[i] = gelu_f((v[i] - mean) * rstd * g1v[i] + b1v[i]);
      uint4 pk4;
      pk4.x = cvt_pk_bf16(gv[0], gv[1]);
      pk4.y = cvt_pk_bf16(gv[2], gv[3]);
      pk4.z = cvt_pk_bf16(gv[4], gv[5]);
      pk4.w = cvt_pk_bf16(gv[6], gv[7]);
      *(uint4*)&y1b[t * 264 + c0] = pk4;
    }
  }
  __syncthreads();
  // ---- Phase B: MFMA GEMM, A-loads 2-deep pipelined ----
  int lane = tid & 63, wid = tid >> 6, col = lane & 15, quad = lane >> 4;
  f32x4 acc[4][2];
#pragma unroll
  for (int mt = 0; mt < 4; ++mt)
#pragma unroll
    for (int nt = 0; nt < 2; ++nt) acc[mt][nt] = (f32x4)(0.f);
  {
    s16x8 avc[4], avn[4];
#pragma unroll
    for (int mt = 0; mt < 4; ++mt)
      avc[mt] = *(const s16x8*)(pw + ((((wid * 4 + mt) * 8 + 0) * 64 + lane) << 3));
#pragma unroll 1
    for (int ks2 = 0; ks2 < 4; ++ks2) {
      int ke = ks2 * 2, ko = ke + 1;
#pragma unroll
      for (int mt = 0; mt < 4; ++mt)
        avn[mt] = *(const s16x8*)(pw + ((((wid * 4 + mt) * 8 + ko) * 64 + lane) << 3));
      {
        int kloc = ke * 32 + quad * 8;
#pragma unroll
        for (int nt = 0; nt < 2; ++nt) {
          s16x8 bv = *(const s16x8*)(y1b + (nt * 16 + col) * 264 + kloc);
#pragma unroll
          for (int mt = 0; mt < 4; ++mt)
            acc[mt][nt] = __builtin_amdgcn_mfma_f32_16x16x32_bf16(avc[mt], bv, acc[mt][nt], 0, 0, 0);
        }
      }
      if (ks2 < 3) {
#pragma unroll
        for (int mt = 0; mt < 4; ++mt)
          avc[mt] = *(const s16x8*)(pw + ((((wid * 4 + mt) * 8 + ko + 1) * 64 + lane) << 3));
      }
      {
        int kloc = ko * 32 + quad * 8;
#pragma unroll
        for (int nt = 0; nt < 2; ++nt) {
          s16x8 bv = *(const s16x8*)(y1b + (nt * 16 + col) * 264 + kloc);
#pragma unroll
          for (int mt = 0; mt < 4; ++mt)
            acc[mt][nt] = __builtin_amdgcn_mfma_f32_16x16x32_bf16(avn[mt], bv, acc[mt][nt], 0, 0, 0);
        }
      }
    }
  }
  __syncthreads();
  // ---- Phase C: bias + per-t stats ----
  float pwbv[4][4];
#pragma unroll
  for (int mt = 0; mt < 4; ++mt)
    *(float4*)pwbv[mt] = *(const float4*)(pwb + (wid * 4 + mt) * 16 + quad * 4);
#pragma unroll
  for (int nt = 0; nt < 2; ++nt) {
    float s = 0.f, q = 0.f;
#pragma unroll
    for (int mt = 0; mt < 4; ++mt)
#pragma unroll
      for (int r = 0; r < 4; ++r) {
        float v = acc[mt][nt][r] + pwbv[mt][r];
        acc[mt][nt][r] = v;
        s += v;
        q = fmaf(v, v, q);
      }
    int pcol = (wid * 4 + quad) * 32 + nt * 16 + col;
    scratch[pcol] = s;
    scratch[512 + pcol] = q;
  }
  __syncthreads();
  if (tid < 32) {
    float s = 0.f, q = 0.f;
#pragma unroll
    for (int p = 0; p < 16; ++p) {
      s += scratch[p * 32 + tid];
      q += scratch[512 + p * 32 + tid];
    }
    float mean = s * (1.f / 256.f);
    float var = q * (1.f / 256.f) - mean * mean;
    stat[tid] = mean;
    stat[32 + tid] = rsqrtf(var + 1e-5f);
  }
  __syncthreads();
  // ---- Phase D: norm2 + gelu -> y1b ----
  {
    float g2v[4][4], b2v[4][4];
#pragma unroll
    for (int mt = 0; mt < 4; ++mt) {
      *(float4*)g2v[mt] = *(const float4*)(g2 + (wid * 4 + mt) * 16 + quad * 4);
      *(float4*)b2v[mt] = *(const float4*)(b2 + (wid * 4 + mt) * 16 + quad * 4);
    }
#pragma unroll
    for (int nt = 0; nt < 2; ++nt) {
      int t = nt * 16 + col;
      float mean = stat[t], rstd = stat[32 + t];
#pragma unroll
      for (int mt = 0; mt < 4; ++mt) {
        int o = (wid * 4 + mt) * 16 + quad * 4;
        float u0 = gelu_f((acc[mt][nt][0] - mean) * rstd * g2v[mt][0] + b2v[mt][0]);
        float u1 = gelu_f((acc[mt][nt][1] - mean) * rstd * g2v[mt][1] + b2v[mt][1]);
        float u2 = gelu_f((acc[mt][nt][2] - mean) * rstd * g2v[mt][2] + b2v[mt][2]);
        float u3 = gelu_f((acc[mt][nt][3] - mean) * rstd * g2v[mt][3] + b2v[mt][3]);
        uint2 wv2;
        wv2.x = cvt_pk_bf16(u0, u1);
        wv2.y = cvt_pk_bf16(u2, u3);
        *(uint2*)&y1b[t * 264 + o] = wv2;
      }
    }
  }
  __syncthreads();
  // ---- Phase E: coalesced residual + store ----
#pragma unroll
  for (int p = 0; p < 4; ++p) {
    int idx = tid + p * 256;
    int trow = idx >> 5, cc = (idx & 31) * 8;
    int t = t0 + trow;
    U8 yv, rv;
    yv.v = *(const uint4*)&y1b[trow * 264 + cc];
    rv.v = *(const uint4*)(hb + (size_t)t * F_ + cc);
    float mval = MASK_OUT ? mrow[t] : 1.f;
    float hv[8];
#pragma unroll
    for (int i = 0; i < 8; ++i) {
      float h = bf2f(rv.u[i]) + bf2f(yv.u[i]);
      hv[i] = MASK_OUT ? h * mval : h;
    }
    uint4 wv4;
    wv4.x = cvt_pk_bf16(hv[0], hv[1]);
    wv4.y = cvt_pk_bf16(hv[2], hv[3]);
    wv4.z = cvt_pk_bf16(hv[4], hv[5]);
    wv4.w = cvt_pk_bf16(hv[6], hv[7]);
    *(uint4*)(hT_out + ((size_t)b * T_ + t) * F_ + cc) = wv4;
  }
}

// ---------------------------------------------------------------------------
// K3: proj GEMM + RQ spline + logdet + x0-copy.
// Staging: COALESCED global reads (row-major, 2x512B/wave — R8's fragment-
// order global scatter cost +7us) + XOR-swizzled fragment-order LDS.
// Block f = nt*512 + ks*64 + quad*16 + col stored at position f ^ ks
// (ks = (f>>6)&7). Write banks: window (col&7)^ks -> 8 windows x 8 lanes =
// 8-cycle min. Read banks (fixed nt,ks; lane=quad*16+col): window
// (col&7)^ks -> same minimum. Zero conflicts both sides (R8 measured 0).
// Read addr: ((nt*8+ks)*64 + (lane^ks))*16B; lane^ko = (lane^ke)^1.
// A-loads 2-deep pipelined (R7). launch_bounds(256,4) — (256,5) spills (R3).
// s-tile [ch][t][j] (2440/38) aliases staging post-barrier.
// ---------------------------------------------------------------------------
__global__ __launch_bounds__(256, 4) void proj_spline_k(
    const ushort* __restrict__ hT,
    const float* __restrict__ x, const float* __restrict__ mask,
    const ushort* __restrict__ w_bf, const float* __restrict__ pbp,
    float* __restrict__ out, float* __restrict__ logdet) {
  __shared__ __align__(16) ushort bsm[19520];   // max(16384 staging, 19520 s-tile)
  __shared__ float red[4];
  ushort* s_lds = bsm;

  int tid = threadIdx.x;
  int t0 = blockIdx.x * 64;
  int chunk = blockIdx.y;
  int b = blockIdx.z;
  int lane = tid & 63, wid = tid >> 6, col = lane & 15, quad = lane >> 4;

  // ---- staging: coalesced global read, swizzled fragment-order LDS write ----
#pragma unroll
  for (int p = 0; p < 8; ++p) {
    int idx = tid + p * 256;
    int row = idx >> 5;                    // t within tile
    int u = idx & 31;                      // 16B block within row
    int ks = u >> 2, q = u & 3;
    int f = ((row >> 4) * 8 + ks) * 64 + q * 16 + (row & 15);
    *(uint4*)(bsm + ((f ^ ks) << 3)) =
        *(const uint4*)(hT + ((size_t)b * T_ + t0 + row) * F_ + u * 8);
  }
  // folded x0-copy
#pragma unroll
  for (int p = 0; p < 2; ++p) {
    int idx = tid + p * 256;
    int ch = idx >> 6, t = idx & 63;
    out[((size_t)b * C_ + chunk * 8 + ch) * T_ + t0 + t] =
        x[((size_t)b * C_ + chunk * 8 + ch) * T_ + t0 + t] * mask[(size_t)b * T_ + t0 + t];
  }
  f32x4 acc[4][4];
#pragma unroll
  for (int mt = 0; mt < 4; ++mt)
#pragma unroll
    for (int nt = 0; nt < 4; ++nt) acc[mt][nt] = (f32x4)(0.f);
  const ushort* wchunk = w_bf + (size_t)chunk * 65536;
  __syncthreads();
  {
    s16x8 avc[4], avn[4];
#pragma unroll
    for (int mt = 0; mt < 4; ++mt)
      avc[mt] = *(const s16x8*)(wchunk + ((((wid * 4 + mt) * 8 + 0) * 64 + lane) << 3));
#pragma unroll 1
    for (int ks2 = 0; ks2 < 4; ++ks2) {
      int ke = ks2 * 2, ko = ke + 1;
      int le = lane ^ ke, lo = le ^ 1;
#pragma unroll
      for (int mt = 0; mt < 4; ++mt)
        avn[mt] = *(const s16x8*)(wchunk + ((((wid * 4 + mt) * 8 + ko) * 64 + lane) << 3));
#pragma unroll
      for (int nt = 0; nt < 4; ++nt) {
        s16x8 bv = *(const s16x8*)(bsm + (((nt * 8 + ke) * 64 + le) << 3));
#pragma unroll
        for (int mt = 0; mt < 4; ++mt)
          acc[mt][nt] = __builtin_amdgcn_mfma_f32_16x16x32_bf16(avc[mt], bv, acc[mt][nt], 0, 0, 0);
      }
      if (ks2 < 3) {
#pragma unroll
        for (int mt = 0; mt < 4; ++mt)
          avc[mt] = *(const s16x8*)(wchunk + ((((wid * 4 + mt) * 8 + ko + 1) * 64 + lane) << 3));
      }
#pragma unroll
      for (int nt = 0; nt < 4; ++nt) {
        s16x8 bv = *(const s16x8*)(bsm + (((nt * 8 + ko) * 64 + lo) << 3));
#pragma unroll
        for (int mt = 0; mt < 4; ++mt)
          acc[mt][nt] = __builtin_amdgcn_mfma_f32_16x16x32_bf16(avn[mt], bv, acc[mt][nt], 0, 0, 0);
      }
    }
  }
  __syncthreads();
  // ---- write s-tile (permuted rows) -> [ch][t][j], strides 2440/38 ----
  {
    float mv[4];
#pragma unroll
    for (int nt = 0; nt < 4; ++nt)
      mv[nt] = mask[(size_t)b * T_ + t0 + nt * 16 + col];
#pragma unroll
    for (int mt = 0; mt < 4; ++mt) {
#pragma unroll
      for (int r = 0; r < 4; ++r) {
        int local = (wid * 4 + mt) * 16 + quad * 4 + r;
        if (local < 232) {
          int ch_i = local & 7, j = local >> 3;
          float bias = pbp[chunk * 232 + local];
          ushort* bp = s_lds + ch_i * 2440 + j;
          unsigned p01 = cvt_pk_bf16((acc[mt][0][r] + bias) * mv[0],
                                     (acc[mt][1][r] + bias) * mv[1]);
          unsigned p23 = cvt_pk_bf16((acc[mt][2][r] + bias) * mv[2],
                                     (acc[mt][3][r] + bias) * mv[3]);
          bp[col * 38]        = (ushort)p01;
          bp[(16 + col) * 38] = (ushort)(p01 >> 16);
          bp[(32 + col) * 38] = (ushort)p23;
          bp[(48 + col) * 38] = (ushort)(p23 >> 16);
        }
      }
    }
  }
  __syncthreads();
  // ---- spline ----
  float lad_sum = 0.f;
  int ch_i = tid >> 5, ti = tid & 31;
  int ch = chunk * 8 + ch_i;
#pragma unroll 1
  for (int pass = 0; pass < 2; ++pass) {
    int t = ti + pass * 32;
    const ushort* sp = s_lds + ch_i * 2440 + t * 38;
    float s[29];
#pragma unroll
    for (int jj = 0; jj < 14; ++jj) {
      unsigned w = *(const unsigned*)(sp + jj * 2);
      s[jj * 2]     = __uint_as_float(w << 16);
      s[jj * 2 + 1] = __uint_as_float(w & 0xffff0000u);
    }
    s[28] = bf2f(sp[28]);
    float xin = x[((size_t)b * C_ + HALF_ + ch) * T_ + t0 + t];
    float mval = mask[(size_t)b * T_ + t0 + t];
    const float KE = 0.09016844f;   // 0.0625 * log2(e)
    float ew[10], eh[10];
    float esw = 0.f, esh = 0.f;
#pragma unroll
    for (int j = 0; j < 10; ++j) { ew[j] = __builtin_amdgcn_exp2f(s[j] * KE); esw += ew[j]; }
#pragma unroll
    for (int j = 0; j < 10; ++j) { eh[j] = __builtin_amdgcn_exp2f(s[10 + j] * KE); esh += eh[j]; }
    // cw_{k+1} = cw_k + 0.01 + 9.9*ew[k]/esw   (== 10*(0.001+0.99*softmax) - 5 chain)
    float aw = 9.9f * __builtin_amdgcn_rcpf(esw);
    float ah = 9.9f * __builtin_amdgcn_rcpf(esh);
    float xc = fminf(fmaxf(xin, -5.f), 5.f);
    bool inside = (xin >= -5.f) && (xin <= 5.f);
    // k = 1
    float cw1 = fmaf(aw, ew[0], -4.99f);
    float ch1 = fmaf(ah, eh[0], -4.99f);
    bool sel1 = (xc >= cw1);
    float in_cw = sel1 ? cw1 : -5.f;
    float in_ch = sel1 ? ch1 : -5.f;
    float hi_cw = cw1, hi_ch = ch1;
    float u0 = s[20];       // dv knot pre-softplus for idx (valid when idx>=1)
    float u1 = s[20];       // dv knot pre-softplus for idx+1 (valid when idx<=8)
    float cwp = cw1 + 0.01f, chp = ch1 + 0.01f;
    bool psel = sel1;
    // k = 2..9: running select of {lower knot (sel_k), upper knot (sel_{k-1})}
#pragma unroll
    for (int k = 2; k <= 9; ++k) {
      float cwk = fmaf(aw, ew[k - 1], cwp);
      float chk = fmaf(ah, eh[k - 1], chp);
      bool sel = (xc >= cwk);
      hi_cw = psel ? cwk : hi_cw;
      hi_ch = psel ? chk : hi_ch;
      u1    = psel ? s[19 + k] : u1;
      in_cw = sel ? cwk : in_cw;
      in_ch = sel ? chk : in_ch;
      u0    = sel ? s[19 + k] : u0;
      psel = sel;
      cwp = cwk + 0.01f;
      chp = chk + 0.01f;
    }
    // k = 10 edge: cw[10] = chh[10] = 5, dv[10] = 1; idx==0 edge: dv[0] = 1
    hi_cw = psel ? 5.f : hi_cw;
    hi_ch = psel ? 5.f : hi_ch;
    float e0 = __expf(u0);
    float sp0 = (u0 > 15.f) ? u0 : __logf(1.f + e0);
    float d0 = sel1 ? (0.001f + sp0) : 1.f;
    float e1 = __expf(u1);
    float sp1 = (u1 > 15.f) ? u1 : __logf(1.f + e1);
    float d1 = psel ? 1.f : (0.001f + sp1);
    float in_w = hi_cw - in_cw;
    float in_h = hi_ch - in_ch;
    float rw = __builtin_amdgcn_rcpf(in_w);
    float theta = (xc - in_cw) * rw;
    float delta = in_h * rw;
    float omt = 1.f - theta;
    float t1m = theta * omt;
    float th2 = theta * theta;
    float denom = delta + (d0 + d1 - 2.f * delta) * t1m;
    float rd = __builtin_amdgcn_rcpf(denom);
    float num = in_h * (delta * th2 + d0 * t1m);
    float outv = in_ch + num * rd;
    float dnum = delta * delta * (d1 * th2 + 2.f * delta * t1m + d0 * omt * omt);
    float lad = __logf(dnum * rd * rd);
    float res = inside ? outv : xin;
    float ladv = inside ? lad : 0.f;
    out[((size_t)b * C_ + HALF_ + ch) * T_ + t0 + t] = res * mval;
    lad_sum += ladv * mval;
  }
#pragma unroll
  for (int off = 32; off > 0; off >>= 1)
    lad_sum += __shfl_down(lad_sum, off, 64);
  if ((tid & 63) == 0) red[tid >> 6] = lad_sum;
  __syncthreads();
  if (tid == 0)
    atomicAdd(logdet + b, red[0] + red[1] + red[2] + red[3]);
}

extern "C" void kernel_launch(void* const* d_in, const int* in_sizes, int n_in,
                              void* d_out, int out_size, void* d_ws, size_t ws_size,
                              hipStream_t stream) {
  const float* x      = (const float*)d_in[0];
  const float* mask   = (const float*)d_in[1];
  const float* pre_w  = (const float*)d_in[2];
  const float* pre_b  = (const float*)d_in[3];
  const float* dw_w   = (const float*)d_in[4];
  const float* dw_b   = (const float*)d_in[5];
  const float* pw_w   = (const float*)d_in[6];
  const float* pw_b   = (const float*)d_in[7];
  const float* g1     = (const float*)d_in[8];
  const float* b1     = (const float*)d_in[9];
  const float* g2     = (const float*)d_in[10];
  const float* b2     = (const float*)d_in[11];
  const float* proj_w = (const float*)d_in[12];
  const float* proj_b = (const float*)d_in[13];
  float* out = (float*)d_out;
  float* logdet = out + (size_t)B_ * C_ * T_;

  const size_t HSZ = (size_t)B_ * T_ * F_;
  ushort* hA    = (ushort*)d_ws;
  ushort* hB    = hA + HSZ;
  ushort* wprj  = hB + HSZ;                  // 786432 (fragment order, padded)
  ushort* wpw   = wprj + 786432;             // 196608
  ushort* wpre  = wpw + 196608;              // 24576
  float*  pbp   = (float*)(wpre + 24576);    // 2784 floats

  hipMemsetAsync(logdet, 0, B_ * sizeof(float), stream);
  wcvt_prj_k<<<dim3(786432 / 256), 256, 0, stream>>>(proj_w, proj_b, wprj, pbp);
  wcvt_pw_k<<<dim3(196608 / 256), 256, 0, stream>>>(pw_w, wpw);
  wcvt_pre_k<<<dim3(24576 / 256), 256, 0, stream>>>(pre_w, wpre);

  pre_k<<<dim3(T_ / 32, B_), 256, 0, stream>>>(x, wpre, pre_b, hA);

  layer_k<false><<<dim3(T_ / 32, B_), 256, 0, stream>>>(hA, hB, mask,
      dw_w, dw_b, g1, b1, wpw, pw_b, g2, b2, 1);
  layer_k<false><<<dim3(T_ / 32, B_), 256, 0, stream>>>(hB, hA, mask,
      dw_w + F_ * 3, dw_b + F_, g1 + F_, b1 + F_,
      wpw + 65536, pw_b + F_, g2 + F_, b2 + F_, 3);
  layer_k<true><<<dim3(T_ / 32, B_), 256, 0, stream>>>(hA, hB, mask,
      dw_w + 2 * F_ * 3, dw_b + 2 * F_, g1 + 2 * F_, b1 + 2 * F_,
      wpw + 2 * 65536, pw_b + 2 * F_, g2 + 2 * F_, b2 + 2 * F_, 9);

  proj_spline_k<<<dim3(T_ / 64, 12, B_), 256, 0, stream>>>(hB, x, mask,
      wprj, pbp, out, logdet);
}

// Round 10
// 299.112 us; speedup vs baseline: 1.0325x; 1.0074x over previous
//
#include <hip/hip_runtime.h>

#define B_ 16
#define C_ 192
#define T_ 2048
#define F_ 256
#define HALF_ 96

typedef short s16x8 __attribute__((ext_vector_type(8)));
typedef float f32x4 __attribute__((ext_vector_type(4)));
typedef unsigned short ushort;

union U8 { uint4 v; ushort u[8]; };
union U4 { uint2 v; ushort u[4]; };

__device__ __forceinline__ ushort f2bf(float f) {
  unsigned u = __float_as_uint(f);
  unsigned r = u + 0x7fff + ((u >> 16) & 1);
  return (ushort)(r >> 16);
}
__device__ __forceinline__ float bf2f(ushort h) {
  return __uint_as_float(((unsigned)h) << 16);
}
// packed f32x2 -> bf16x2 (RNE), single HW inst; lo <- %1, hi <- %2
__device__ __forceinline__ unsigned cvt_pk_bf16(float lo, float hi) {
  unsigned r;
  asm("v_cvt_pk_bf16_f32 %0, %1, %2" : "=v"(r) : "v"(lo), "v"(hi));
  return r;
}
// tanh-form gelu on raw v_exp_f32
__device__ __forceinline__ float gelu_f(float x) {
  float x3 = x * x * x;
  float z = fmaf(0.0356774081f, x3, 0.7978845608f * x);
  float az = fabsf(z);
  float e = __builtin_amdgcn_exp2f(az * -2.885390082f);  // exp(-2az)
  float th = (1.f - e) * __builtin_amdgcn_rcpf(1.f + e);
  th = copysignf(th, z);
  return 0.5f * x * (1.f + th);
}

// ---------------------------------------------------------------------------
// Weight converters -> MFMA-fragment order: wq[tile][ks][lane][8], so a wave's
// A-load is base + lane*16B (fully coalesced). lane = quad*16+col encodes
// row = tile*16+col, k = ks*32+quad*8+e.
// ---------------------------------------------------------------------------
__global__ void wcvt_prj_k(const float* __restrict__ w, const float* __restrict__ pb,
                           ushort* __restrict__ wq, float* __restrict__ pbp) {
  int d = blockIdx.x * 256 + threadIdx.x;   // 12*16*8*64*8 = 786432
  if (d >= 786432) return;
  int e = d & 7;
  int lane = (d >> 3) & 63;
  int ks = (d >> 9) & 7;
  int mtile = (d >> 12) & 15;
  int chunk = d >> 16;
  int col = lane & 15, quad = lane >> 4;
  int pr_loc = mtile * 16 + col;            // permuted local row = j*8+ch_i
  int k = ks * 32 + quad * 8 + e;
  float val = 0.f;
  if (pr_loc < 232) {
    int j = pr_loc >> 3, ch_i = pr_loc & 7;
    int r = chunk * 232 + ch_i * 29 + j;    // original row
    val = w[(size_t)r * 256 + k];
    if (ks == 0 && quad == 0 && e == 0) pbp[chunk * 232 + pr_loc] = pb[r];
  }
  wq[d] = f2bf(val);
}

__global__ void wcvt_pw_k(const float* __restrict__ pw_w, ushort* __restrict__ wq) {
  int d = blockIdx.x * 256 + threadIdx.x;   // 3*16*8*64*8 = 196608
  if (d >= 196608) return;
  int e = d & 7;
  int lane = (d >> 3) & 63;
  int ks = (d >> 9) & 7;
  int mtile = (d >> 12) & 15;
  int l = d >> 16;
  int col = lane & 15, quad = lane >> 4;
  int row = mtile * 16 + col, k = ks * 32 + quad * 8 + e;
  wq[d] = f2bf(pw_w[(size_t)(l * 256 + row) * 256 + k]);
}

__global__ void wcvt_pre_k(const float* __restrict__ pre_w, ushort* __restrict__ wq) {
  int d = blockIdx.x * 256 + threadIdx.x;   // 16*3*64*8 = 24576
  if (d >= 24576) return;
  int e = d & 7;
  int idx = d >> 3;
  int lane = idx & 63; idx >>= 6;
  int ks = idx % 3, mtile = idx / 3;
  int col = lane & 15, quad = lane >> 4;
  int row = mtile * 16 + col, k = ks * 32 + quad * 8 + e;
  wq[d] = f2bf(pre_w[row * 96 + k]);
}

// ---------------------------------------------------------------------------
// K1: pre GEMM via MFMA, 32-t tiles. x0 fp32 [c][t] -> hT bf16 [b][t][c]
// ---------------------------------------------------------------------------
__global__ __launch_bounds__(256, 4) void pre_k(
    const float* __restrict__ x, const ushort* __restrict__ wb,
    const float* __restrict__ pb, ushort* __restrict__ hT) {
  __shared__ ushort xb[32 * 104];
  __shared__ __align__(16) ushort ob[32 * 264];
  int tid = threadIdx.x;
  int b = blockIdx.y;
  int t0 = blockIdx.x * 32;
#pragma unroll
  for (int p = 0; p < 12; ++p) {
    int idx = tid + p * 256;
    int c = idx >> 5, t = idx & 31;
    xb[t * 104 + c] = f2bf(x[((size_t)b * C_ + c) * T_ + t0 + t]);
  }
  __syncthreads();
  int lane = tid & 63, wid = tid >> 6, col = lane & 15, quad = lane >> 4;
  f32x4 acc[4][2];
#pragma unroll
  for (int mt = 0; mt < 4; ++mt)
#pragma unroll
    for (int nt = 0; nt < 2; ++nt) acc[mt][nt] = (f32x4)(0.f);
#pragma unroll
  for (int ks = 0; ks < 3; ++ks) {
    int kloc = ks * 32 + quad * 8;
    s16x8 av[4];
#pragma unroll
    for (int mt = 0; mt < 4; ++mt)
      av[mt] = *(const s16x8*)(wb + ((((wid * 4 + mt) * 3 + ks) * 64 + lane) << 3));
#pragma unroll
    for (int nt = 0; nt < 2; ++nt) {
      s16x8 bv = *(const s16x8*)(xb + (nt * 16 + col) * 104 + kloc);
#pragma unroll
      for (int mt = 0; mt < 4; ++mt)
        acc[mt][nt] = __builtin_amdgcn_mfma_f32_16x16x32_bf16(av[mt], bv, acc[mt][nt], 0, 0, 0);
    }
  }
  float pbv[4][4];
#pragma unroll
  for (int mt = 0; mt < 4; ++mt)
    *(float4*)pbv[mt] = *(const float4*)(pb + (wid * 4 + mt) * 16 + quad * 4);
#pragma unroll
  for (int nt = 0; nt < 2; ++nt) {
    int t = nt * 16 + col;
#pragma unroll
    for (int mt = 0; mt < 4; ++mt) {
      int o = (wid * 4 + mt) * 16 + quad * 4;
      uint2 wv2;
      wv2.x = cvt_pk_bf16(acc[mt][nt][0] + pbv[mt][0], acc[mt][nt][1] + pbv[mt][1]);
      wv2.y = cvt_pk_bf16(acc[mt][nt][2] + pbv[mt][2], acc[mt][nt][3] + pbv[mt][3]);
      *(uint2*)&ob[t * 264 + o] = wv2;
    }
  }
  __syncthreads();
#pragma unroll
  for (int p = 0; p < 4; ++p) {
    int idx = tid + p * 256;
    int trow = idx >> 5, cc = (idx & 31) * 8;
    *(uint4*)(hT + ((size_t)b * T_ + t0 + trow) * F_ + cc) =
        *(const uint4*)&ob[trow * 264 + cc];
  }
}

// ---------------------------------------------------------------------------
// K2: fused layer, 32-t tiles. GEMM A-loads 2-deep pipelined (even/odd ks).
// ---------------------------------------------------------------------------
template <bool MASK_OUT>
__global__ __launch_bounds__(256, 4) void layer_k(
    const ushort* __restrict__ hT_in, ushort* __restrict__ hT_out,
    const float* __restrict__ mask,
    const float* __restrict__ dww, const float* __restrict__ dwb,
    const float* __restrict__ g1, const float* __restrict__ b1,
    const ushort* __restrict__ pw, const float* __restrict__ pwb,
    const float* __restrict__ g2, const float* __restrict__ b2,
    int dil) {
  __shared__ __align__(16) ushort y1b[32 * 264];
  __shared__ float stat[64];
  float* scratch = (float*)y1b;
  int tid = threadIdx.x;
  int b = blockIdx.y;
  int t0 = blockIdx.x * 32;
  const ushort* hb = hT_in + (size_t)b * T_ * F_;
  const float* mrow = mask + (size_t)b * T_;

  // ---- Phase A: conv + norm1 + gelu ----
  {
    int lane32 = tid & 31;
    int half = tid >> 5;
    int c0 = lane32 * 8;
    float dwl[24], dbv[8], g1v[8], b1v[8];
#pragma unroll
    for (int q = 0; q < 6; ++q)
      *(float4*)&dwl[q * 4] = *(const float4*)(dww + c0 * 3 + q * 4);
    *(float4*)&dbv[0] = *(const float4*)(dwb + c0);
    *(float4*)&dbv[4] = *(const float4*)(dwb + c0 + 4);
    *(float4*)&g1v[0] = *(const float4*)(g1 + c0);
    *(float4*)&g1v[4] = *(const float4*)(g1 + c0 + 4);
    *(float4*)&b1v[0] = *(const float4*)(b1 + c0);
    *(float4*)&b1v[4] = *(const float4*)(b1 + c0 + 4);
    uint4 zero4 = make_uint4(0, 0, 0, 0);
#pragma unroll 1
    for (int pass = 0; pass < 4; ++pass) {
      int t = pass * 8 + half;
      int tz = t0 + t, tm = tz - dil, tp = tz + dil;
      bool vm = (tm >= 0), vp = (tp < T_);
      float mm = vm ? mrow[tm] : 0.f;
      float mz = mrow[tz];
      float mp = vp ? mrow[tp] : 0.f;
      U8 r0, r1, r2;
      r0.v = vm ? *(const uint4*)(hb + (size_t)tm * F_ + c0) : zero4;
      r1.v = *(const uint4*)(hb + (size_t)tz * F_ + c0);
      r2.v = vp ? *(const uint4*)(hb + (size_t)tp * F_ + c0) : zero4;
      float v[8];
      float s = 0.f, q = 0.f;
#pragma unroll
      for (int i = 0; i < 8; ++i) {
        float vv = fmaf(dwl[i * 3], bf2f(r0.u[i]) * mm,
                   fmaf(dwl[i * 3 + 1], bf2f(r1.u[i]) * mz,
                   fmaf(dwl[i * 3 + 2], bf2f(r2.u[i]) * mp, dbv[i])));
        v[i] = vv;
        s += vv;
        q = fmaf(vv, vv, q);
      }
#pragma unroll
      for (int m = 1; m < 32; m <<= 1) {
        s += __shfl_xor(s, m, 32);
        q += __shfl_xor(q, m, 32);
      }
      float mean = s * (1.f / 256.f);
      float var = q * (1.f / 256.f) - mean * mean;
      float rstd = rsqrtf(var + 1e-5f);
      float gv[8];
#pragma unroll
      for (int i = 0; i < 8; ++i)
        gv[i] = gelu_f((v[i] - mean) * rstd * g1v[i] + b1v[i]);
      uint4 pk4;
      pk4.x = cvt_pk_bf16(gv[0], gv[1]);
      pk4.y = cvt_pk_bf16(gv[2], gv[3]);
      pk4.z = cvt_pk_bf16(gv[4], gv[5]);
      pk4.w = cvt_pk_bf16(gv[6], gv[7]);
      *(uint4*)&y1b[t * 264 + c0] = pk4;
    }
  }
  __syncthreads();
  // ---- Phase B: MFMA GEMM, A-loads 2-deep pipelined ----
  int lane = tid & 63, wid = tid >> 6, col = lane & 15, quad = lane >> 4;
  f32x4 acc[4][2];
#pragma unroll
  for (int mt = 0; mt < 4; ++mt)
#pragma unroll
    for (int nt = 0; nt < 2; ++nt) acc[mt][nt] = (f32x4)(0.f);
  {
    s16x8 avc[4], avn[4];
#pragma unroll
    for (int mt = 0; mt < 4; ++mt)
      avc[mt] = *(const s16x8*)(pw + ((((wid * 4 + mt) * 8 + 0) * 64 + lane) << 3));
#pragma unroll 1
    for (int ks2 = 0; ks2 < 4; ++ks2) {
      int ke = ks2 * 2, ko = ke + 1;
#pragma unroll
      for (int mt = 0; mt < 4; ++mt)
        avn[mt] = *(const s16x8*)(pw + ((((wid * 4 + mt) * 8 + ko) * 64 + lane) << 3));
      {
        int kloc = ke * 32 + quad * 8;
#pragma unroll
        for (int nt = 0; nt < 2; ++nt) {
          s16x8 bv = *(const s16x8*)(y1b + (nt * 16 + col) * 264 + kloc);
#pragma unroll
          for (int mt = 0; mt < 4; ++mt)
            acc[mt][nt] = __builtin_amdgcn_mfma_f32_16x16x32_bf16(avc[mt], bv, acc[mt][nt], 0, 0, 0);
        }
      }
      if (ks2 < 3) {
#pragma unroll
        for (int mt = 0; mt < 4; ++mt)
          avc[mt] = *(const s16x8*)(pw + ((((wid * 4 + mt) * 8 + ko + 1) * 64 + lane) << 3));
      }
      {
        int kloc = ko * 32 + quad * 8;
#pragma unroll
        for (int nt = 0; nt < 2; ++nt) {
          s16x8 bv = *(const s16x8*)(y1b + (nt * 16 + col) * 264 + kloc);
#pragma unroll
          for (int mt = 0; mt < 4; ++mt)
            acc[mt][nt] = __builtin_amdgcn_mfma_f32_16x16x32_bf16(avn[mt], bv, acc[mt][nt], 0, 0, 0);
        }
      }
    }
  }
  __syncthreads();
  // ---- Phase C: bias + per-t stats ----
  float pwbv[4][4];
#pragma unroll
  for (int mt = 0; mt < 4; ++mt)
    *(float4*)pwbv[mt] = *(const float4*)(pwb + (wid * 4 + mt) * 16 + quad * 4);
#pragma unroll
  for (int nt = 0; nt < 2; ++nt) {
    float s = 0.f, q = 0.f;
#pragma unroll
    for (int mt = 0; mt < 4; ++mt)
#pragma unroll
      for (int r = 0; r < 4; ++r) {
        float v = acc[mt][nt][r] + pwbv[mt][r];
        acc[mt][nt][r] = v;
        s += v;
        q = fmaf(v, v, q);
      }
    int pcol = (wid * 4 + quad) * 32 + nt * 16 + col;
    scratch[pcol] = s;
    scratch[512 + pcol] = q;
  }
  __syncthreads();
  if (tid < 32) {
    float s = 0.f, q = 0.f;
#pragma unroll
    for (int p = 0; p < 16; ++p) {
      s += scratch[p * 32 + tid];
      q += scratch[512 + p * 32 + tid];
    }
    float mean = s * (1.f / 256.f);
    float var = q * (1.f / 256.f) - mean * mean;
    stat[tid] = mean;
    stat[32 + tid] = rsqrtf(var + 1e-5f);
  }
  __syncthreads();
  // ---- Phase D: norm2 + gelu -> y1b ----
  {
    float g2v[4][4], b2v[4][4];
#pragma unroll
    for (int mt = 0; mt < 4; ++mt) {
      *(float4*)g2v[mt] = *(const float4*)(g2 + (wid * 4 + mt) * 16 + quad * 4);
      *(float4*)b2v[mt] = *(const float4*)(b2 + (wid * 4 + mt) * 16 + quad * 4);
    }
#pragma unroll
    for (int nt = 0; nt < 2; ++nt) {
      int t = nt * 16 + col;
      float mean = stat[t], rstd = stat[32 + t];
#pragma unroll
      for (int mt = 0; mt < 4; ++mt) {
        int o = (wid * 4 + mt) * 16 + quad * 4;
        float u0 = gelu_f((acc[mt][nt][0] - mean) * rstd * g2v[mt][0] + b2v[mt][0]);
        float u1 = gelu_f((acc[mt][nt][1] - mean) * rstd * g2v[mt][1] + b2v[mt][1]);
        float u2 = gelu_f((acc[mt][nt][2] - mean) * rstd * g2v[mt][2] + b2v[mt][2]);
        float u3 = gelu_f((acc[mt][nt][3] - mean) * rstd * g2v[mt][3] + b2v[mt][3]);
        uint2 wv2;
        wv2.x = cvt_pk_bf16(u0, u1);
        wv2.y = cvt_pk_bf16(u2, u3);
        *(uint2*)&y1b[t * 264 + o] = wv2;
      }
    }
  }
  __syncthreads();
  // ---- Phase E: coalesced residual + store ----
#pragma unroll
  for (int p = 0; p < 4; ++p) {
    int idx = tid + p * 256;
    int trow = idx >> 5, cc = (idx & 31) * 8;
    int t = t0 + trow;
    U8 yv, rv;
    yv.v = *(const uint4*)&y1b[trow * 264 + cc];
    rv.v = *(const uint4*)(hb + (size_t)t * F_ + cc);
    float mval = MASK_OUT ? mrow[t] : 1.f;
    float hv[8];
#pragma unroll
    for (int i = 0; i < 8; ++i) {
      float h = bf2f(rv.u[i]) + bf2f(yv.u[i]);
      hv[i] = MASK_OUT ? h * mval : h;
    }
    uint4 wv4;
    wv4.x = cvt_pk_bf16(hv[0], hv[1]);
    wv4.y = cvt_pk_bf16(hv[2], hv[3]);
    wv4.z = cvt_pk_bf16(hv[4], hv[5]);
    wv4.w = cvt_pk_bf16(hv[6], hv[7]);
    *(uint4*)(hT_out + ((size_t)b * T_ + t) * F_ + cc) = wv4;
  }
}

// ---------------------------------------------------------------------------
// K3: proj GEMM + RQ spline + logdet + x0-copy.
// Staging: coalesced global reads + swizzled fragment-order LDS.
// HW model (validated on R7/R8/R9 conflict counts 512/0/768 per block):
// LDS serves b128 ops in consecutive-8-lane groups; each group must cover
// all 8 bank-quads (pos%8). Swizzle: block (nt,ks,q,c) at position
// (nt*8+ks)*64 + q*16 + (c ^ (4*(ks&1)+q)).
//   write groups (fixed c; (ks,q) spans 2x4): pos%8 = c8^{4b+q} = all 8  OK
//   read  groups (fixed nt,ks,q; c spans 8): pos%8 bijective in c        OK
// Read offset loop-invariant: lswz = (lane&48)|((lane&15)^quad); even ks
// reads at base+lswz, odd at base+(lswz^4).
// A-loads 2-deep pipelined (R7). launch_bounds(256,4) — (256,5) spills (R3).
// s-tile [ch][t][j] (2440/38) aliases staging post-barrier.
// ---------------------------------------------------------------------------
__global__ __launch_bounds__(256, 4) void proj_spline_k(
    const ushort* __restrict__ hT,
    const float* __restrict__ x, const float* __restrict__ mask,
    const ushort* __restrict__ w_bf, const float* __restrict__ pbp,
    float* __restrict__ out, float* __restrict__ logdet) {
  __shared__ __align__(16) ushort bsm[19520];   // max(16384 staging, 19520 s-tile)
  __shared__ float red[4];
  ushort* s_lds = bsm;

  int tid = threadIdx.x;
  int t0 = blockIdx.x * 64;
  int chunk = blockIdx.y;
  int b = blockIdx.z;
  int lane = tid & 63, wid = tid >> 6, col = lane & 15, quad = lane >> 4;

  // ---- staging: coalesced global read, swizzled fragment-order LDS write ----
#pragma unroll
  for (int p = 0; p < 8; ++p) {
    int idx = tid + p * 256;
    int row = idx >> 5;                    // t within tile
    int u = idx & 31;                      // 16B block within row
    int ks = u >> 2, q = u & 3;
    int pos = (((row >> 4) * 8 + ks) << 6) + (q << 4)
            + ((row & 15) ^ ((ks & 1) * 4 + q));
    *(uint4*)(bsm + (pos << 3)) =
        *(const uint4*)(hT + ((size_t)b * T_ + t0 + row) * F_ + u * 8);
  }
  // folded x0-copy
#pragma unroll
  for (int p = 0; p < 2; ++p) {
    int idx = tid + p * 256;
    int ch = idx >> 6, t = idx & 63;
    out[((size_t)b * C_ + chunk * 8 + ch) * T_ + t0 + t] =
        x[((size_t)b * C_ + chunk * 8 + ch) * T_ + t0 + t] * mask[(size_t)b * T_ + t0 + t];
  }
  f32x4 acc[4][4];
#pragma unroll
  for (int mt = 0; mt < 4; ++mt)
#pragma unroll
    for (int nt = 0; nt < 4; ++nt) acc[mt][nt] = (f32x4)(0.f);
  const ushort* wchunk = w_bf + (size_t)chunk * 65536;
  int lswz = (lane & 48) | ((lane & 15) ^ quad);   // even-ks read offset
  int lswzo = lswz ^ 4;                            // odd-ks read offset
  __syncthreads();
  {
    s16x8 avc[4], avn[4];
#pragma unroll
    for (int mt = 0; mt < 4; ++mt)
      avc[mt] = *(const s16x8*)(wchunk + ((((wid * 4 + mt) * 8 + 0) * 64 + lane) << 3));
#pragma unroll 1
    for (int ks2 = 0; ks2 < 4; ++ks2) {
      int ke = ks2 * 2, ko = ke + 1;
#pragma unroll
      for (int mt = 0; mt < 4; ++mt)
        avn[mt] = *(const s16x8*)(wchunk + ((((wid * 4 + mt) * 8 + ko) * 64 + lane) << 3));
#pragma unroll
      for (int nt = 0; nt < 4; ++nt) {
        s16x8 bv = *(const s16x8*)(bsm + (((nt * 8 + ke) * 64 + lswz) << 3));
#pragma unroll
        for (int mt = 0; mt < 4; ++mt)
          acc[mt][nt] = __builtin_amdgcn_mfma_f32_16x16x32_bf16(avc[mt], bv, acc[mt][nt], 0, 0, 0);
      }
      if (ks2 < 3) {
#pragma unroll
        for (int mt = 0; mt < 4; ++mt)
          avc[mt] = *(const s16x8*)(wchunk + ((((wid * 4 + mt) * 8 + ko + 1) * 64 + lane) << 3));
      }
#pragma unroll
      for (int nt = 0; nt < 4; ++nt) {
        s16x8 bv = *(const s16x8*)(bsm + (((nt * 8 + ko) * 64 + lswzo) << 3));
#pragma unroll
        for (int mt = 0; mt < 4; ++mt)
          acc[mt][nt] = __builtin_amdgcn_mfma_f32_16x16x32_bf16(avn[mt], bv, acc[mt][nt], 0, 0, 0);
      }
    }
  }
  __syncthreads();
  // ---- write s-tile (permuted rows) -> [ch][t][j], strides 2440/38 ----
  {
    float mv[4];
#pragma unroll
    for (int nt = 0; nt < 4; ++nt)
      mv[nt] = mask[(size_t)b * T_ + t0 + nt * 16 + col];
#pragma unroll
    for (int mt = 0; mt < 4; ++mt) {
#pragma unroll
      for (int r = 0; r < 4; ++r) {
        int local = (wid * 4 + mt) * 16 + quad * 4 + r;
        if (local < 232) {
          int ch_i = local & 7, j = local >> 3;
          float bias = pbp[chunk * 232 + local];
          ushort* bp = s_lds + ch_i * 2440 + j;
          unsigned p01 = cvt_pk_bf16((acc[mt][0][r] + bias) * mv[0],
                                     (acc[mt][1][r] + bias) * mv[1]);
          unsigned p23 = cvt_pk_bf16((acc[mt][2][r] + bias) * mv[2],
                                     (acc[mt][3][r] + bias) * mv[3]);
          bp[col * 38]        = (ushort)p01;
          bp[(16 + col) * 38] = (ushort)(p01 >> 16);
          bp[(32 + col) * 38] = (ushort)p23;
          bp[(48 + col) * 38] = (ushort)(p23 >> 16);
        }
      }
    }
  }
  __syncthreads();
  // ---- spline ----
  float lad_sum = 0.f;
  int ch_i = tid >> 5, ti = tid & 31;
  int ch = chunk * 8 + ch_i;
#pragma unroll 1
  for (int pass = 0; pass < 2; ++pass) {
    int t = ti + pass * 32;
    const ushort* sp = s_lds + ch_i * 2440 + t * 38;
    float s[29];
#pragma unroll
    for (int jj = 0; jj < 14; ++jj) {
      unsigned w = *(const unsigned*)(sp + jj * 2);
      s[jj * 2]     = __uint_as_float(w << 16);
      s[jj * 2 + 1] = __uint_as_float(w & 0xffff0000u);
    }
    s[28] = bf2f(sp[28]);
    float xin = x[((size_t)b * C_ + HALF_ + ch) * T_ + t0 + t];
    float mval = mask[(size_t)b * T_ + t0 + t];
    const float KE = 0.09016844f;   // 0.0625 * log2(e)
    float ew[10], eh[10];
    float esw = 0.f, esh = 0.f;
#pragma unroll
    for (int j = 0; j < 10; ++j) { ew[j] = __builtin_amdgcn_exp2f(s[j] * KE); esw += ew[j]; }
#pragma unroll
    for (int j = 0; j < 10; ++j) { eh[j] = __builtin_amdgcn_exp2f(s[10 + j] * KE); esh += eh[j]; }
    // cw_{k+1} = cw_k + 0.01 + 9.9*ew[k]/esw   (== 10*(0.001+0.99*softmax) - 5 chain)
    float aw = 9.9f * __builtin_amdgcn_rcpf(esw);
    float ah = 9.9f * __builtin_amdgcn_rcpf(esh);
    float xc = fminf(fmaxf(xin, -5.f), 5.f);
    bool inside = (xin >= -5.f) && (xin <= 5.f);
    // k = 1
    float cw1 = fmaf(aw, ew[0], -4.99f);
    float ch1 = fmaf(ah, eh[0], -4.99f);
    bool sel1 = (xc >= cw1);
    float in_cw = sel1 ? cw1 : -5.f;
    float in_ch = sel1 ? ch1 : -5.f;
    float hi_cw = cw1, hi_ch = ch1;
    float u0 = s[20];       // dv knot pre-softplus for idx (valid when idx>=1)
    float u1 = s[20];       // dv knot pre-softplus for idx+1 (valid when idx<=8)
    float cwp = cw1 + 0.01f, chp = ch1 + 0.01f;
    bool psel = sel1;
    // k = 2..9: running select of {lower knot (sel_k), upper knot (sel_{k-1})}
#pragma unroll
    for (int k = 2; k <= 9; ++k) {
      float cwk = fmaf(aw, ew[k - 1], cwp);
      float chk = fmaf(ah, eh[k - 1], chp);
      bool sel = (xc >= cwk);
      hi_cw = psel ? cwk : hi_cw;
      hi_ch = psel ? chk : hi_ch;
      u1    = psel ? s[19 + k] : u1;
      in_cw = sel ? cwk : in_cw;
      in_ch = sel ? chk : in_ch;
      u0    = sel ? s[19 + k] : u0;
      psel = sel;
      cwp = cwk + 0.01f;
      chp = chk + 0.01f;
    }
    // k = 10 edge: cw[10] = chh[10] = 5, dv[10] = 1; idx==0 edge: dv[0] = 1
    hi_cw = psel ? 5.f : hi_cw;
    hi_ch = psel ? 5.f : hi_ch;
    float e0 = __expf(u0);
    float sp0 = (u0 > 15.f) ? u0 : __logf(1.f + e0);
    float d0 = sel1 ? (0.001f + sp0) : 1.f;
    float e1 = __expf(u1);
    float sp1 = (u1 > 15.f) ? u1 : __logf(1.f + e1);
    float d1 = psel ? 1.f : (0.001f + sp1);
    float in_w = hi_cw - in_cw;
    float in_h = hi_ch - in_ch;
    float rw = __builtin_amdgcn_rcpf(in_w);
    float theta = (xc - in_cw) * rw;
    float delta = in_h * rw;
    float omt = 1.f - theta;
    float t1m = theta * omt;
    float th2 = theta * theta;
    float denom = delta + (d0 + d1 - 2.f * delta) * t1m;
    float rd = __builtin_amdgcn_rcpf(denom);
    float num = in_h * (delta * th2 + d0 * t1m);
    float outv = in_ch + num * rd;
    float dnum = delta * delta * (d1 * th2 + 2.f * delta * t1m + d0 * omt * omt);
    float lad = __logf(dnum * rd * rd);
    float res = inside ? outv : xin;
    float ladv = inside ? lad : 0.f;
    out[((size_t)b * C_ + HALF_ + ch) * T_ + t0 + t] = res * mval;
    lad_sum += ladv * mval;
  }
#pragma unroll
  for (int off = 32; off > 0; off >>= 1)
    lad_sum += __shfl_down(lad_sum, off, 64);
  if ((tid & 63) == 0) red[tid >> 6] = lad_sum;
  __syncthreads();
  if (tid == 0)
    atomicAdd(logdet + b, red[0] + red[1] + red[2] + red[3]);
}

extern "C" void kernel_launch(void* const* d_in, const int* in_sizes, int n_in,
                              void* d_out, int out_size, void* d_ws, size_t ws_size,
                              hipStream_t stream) {
  const float* x      = (const float*)d_in[0];
  const float* mask   = (const float*)d_in[1];
  const float* pre_w  = (const float*)d_in[2];
  const float* pre_b  = (const float*)d_in[3];
  const float* dw_w   = (const float*)d_in[4];
  const float* dw_b   = (const float*)d_in[5];
  const float* pw_w   = (const float*)d_in[6];
  const float* pw_b   = (const float*)d_in[7];
  const float* g1     = (const float*)d_in[8];
  const float* b1     = (const float*)d_in[9];
  const float* g2     = (const float*)d_in[10];
  const float* b2     = (const float*)d_in[11];
  const float* proj_w = (const float*)d_in[12];
  const float* proj_b = (const float*)d_in[13];
  float* out = (float*)d_out;
  float* logdet = out + (size_t)B_ * C_ * T_;

  const size_t HSZ = (size_t)B_ * T_ * F_;
  ushort* hA    = (ushort*)d_ws;
  ushort* hB    = hA + HSZ;
  ushort* wprj  = hB + HSZ;                  // 786432 (fragment order, padded)
  ushort* wpw   = wprj + 786432;             // 196608
  ushort* wpre  = wpw + 196608;              // 24576
  float*  pbp   = (float*)(wpre + 24576);    // 2784 floats

  hipMemsetAsync(logdet, 0, B_ * sizeof(float), stream);
  wcvt_prj_k<<<dim3(786432 / 256), 256, 0, stream>>>(proj_w, proj_b, wprj, pbp);
  wcvt_pw_k<<<dim3(196608 / 256), 256, 0, stream>>>(pw_w, wpw);
  wcvt_pre_k<<<dim3(24576 / 256), 256, 0, stream>>>(pre_w, wpre);

  pre_k<<<dim3(T_ / 32, B_), 256, 0, stream>>>(x, wpre, pre_b, hA);

  layer_k<false><<<dim3(T_ / 32, B_), 256, 0, stream>>>(hA, hB, mask,
      dw_w, dw_b, g1, b1, wpw, pw_b, g2, b2, 1);
  layer_k<false><<<dim3(T_ / 32, B_), 256, 0, stream>>>(hB, hA, mask,
      dw_w + F_ * 3, dw_b + F_, g1 + F_, b1 + F_,
      wpw + 65536, pw_b + F_, g2 + F_, b2 + F_, 3);
  layer_k<true><<<dim3(T_ / 32, B_), 256, 0, stream>>>(hA, hB, mask,
      dw_w + 2 * F_ * 3, dw_b + 2 * F_, g1 + 2 * F_, b1 + 2 * F_,
      wpw + 2 * 65536, pw_b + 2 * F_, g2 + 2 * F_, b2 + 2 * F_, 9);

  proj_spline_k<<<dim3(T_ / 64, 12, B_), 256, 0, stream>>>(hB, x, mask,
      wprj, pbp, out, logdet);
}